// Round 4
// baseline (472.848 us; speedup 1.0000x reference)
//
#include <hip/hip_runtime.h>
#include <math.h>

#define GW 38
#define GH 38
#define NA 25
#define NB 512
#define HW (GW * GH)              // 1444
#define S4 (HW / 4)               // 361 float4 per channel-plane
#define PLANES (NB * NA)          // 12800 (b,a) planes
#define HALF_PLANES (PLANES / 2)  // 6400 → +6400 planes == +256 batches
#define T_TOTAL (HALF_PLANES * S4)  // 2,310,400 threads
#define BLK 256
#define NBLOCKS (T_TOTAL / BLK)   // 9025 loss blocks

typedef float f32x4 __attribute__((ext_vector_type(4)));

struct Meta {
    float gxlo, gxhi, gylo, gyhi;  // gx -/+ gw/2, gy -/+ gh/2
    float gw, gh, area;            // gw*gh
    float tconf, tb0, tb1, tb2, tb3;
    int   best, cell;              // cell = gj*38 + gi
};
static_assert(sizeof(Meta) == 56, "Meta layout drifted; workspace offsets depend on it");

__device__ __forceinline__ float fast_rcp(float x) { return __builtin_amdgcn_rcpf(x); }
__device__ __forceinline__ float fast_exp(float x) { return __expf(x); }          // v_exp_f32
__device__ __forceinline__ float fast_sig(float x) { return fast_rcp(1.0f + fast_exp(-x)); }

__device__ __forceinline__ float iou_precise(float x1, float y1, float w1, float h1,
                                             float x2, float y2, float w2, float h2) {
    float mx = fminf(x1 - w1 * 0.5f, x2 - w2 * 0.5f);
    float Mx = fmaxf(x1 + w1 * 0.5f, x2 + w2 * 0.5f);
    float my = fminf(y1 - h1 * 0.5f, y2 - h2 * 0.5f);
    float My = fmaxf(y1 + h1 * 0.5f, y2 + h2 * 0.5f);
    float cw = w1 + w2 - (Mx - mx);
    float ch = h1 + h2 - (My - my);
    float inter = (cw > 0.0f && ch > 0.0f) ? cw * ch : 0.0f;
    float uni = w1 * h1 + w2 * h2 - inter;
    return inter / uni;
}

// anchors = float32(_BASE) * float32(scale), scale in {0.5,0.75,1.0,1.25,1.5}
__device__ __forceinline__ void anchor_wh(int a, float* aw, float* ah) {
    const float bw[5] = {1.3221f, 3.19275f, 5.05587f, 9.47112f, 11.2364f};
    const float bh[5] = {1.73145f, 4.00944f, 8.09892f, 4.84053f, 10.0071f};
    float s = 0.5f + 0.25f * (float)(a / 5);
    *aw = bw[a % 5] * s;
    *ah = bh[a % 5] * s;
}

__global__ void meta_kernel(const float* __restrict__ pred,
                            const float* __restrict__ target,
                            Meta* __restrict__ metas) {
    int b = blockIdx.x * blockDim.x + threadIdx.x;
    if (b >= NB) return;
    float gx = target[b * 4 + 0] * (float)GW;
    float gy = target[b * 4 + 1] * (float)GH;
    float gw = target[b * 4 + 2] * (float)GW;
    float gh = target[b * 4 + 3] * (float)GH;
    int best = 0;
    float best_iou = -1.0f;
    for (int a = 0; a < NA; ++a) {
        float aw, ah;
        anchor_wh(a, &aw, &ah);
        float v = iou_precise(0.0f, 0.0f, aw, ah, 0.0f, 0.0f, gw, gh);
        if (v > best_iou) { best_iou = v; best = a; }
    }
    int gi = (int)gx;
    int gj = (int)gy;
    float aw, ah;
    anchor_wh(best, &aw, &ah);
    size_t base = (size_t)b * NA * 5 * HW + (size_t)(best * 5) * HW + gj * GW + gi;
    float p0 = pred[base + 0 * HW];
    float p1 = pred[base + 1 * HW];
    float p2 = pred[base + 2 * HW];
    float p3 = pred[base + 3 * HW];
    float pbx = 1.0f / (1.0f + expf(-p0)) + (float)gi;   // precise path (512 cells only)
    float pby = 1.0f / (1.0f + expf(-p1)) + (float)gj;
    float pbw = expf(p2) * aw;
    float pbh = expf(p3) * ah;
    Meta m;
    m.gxlo = gx - gw * 0.5f; m.gxhi = gx + gw * 0.5f;
    m.gylo = gy - gh * 0.5f; m.gyhi = gy + gh * 0.5f;
    m.gw = gw; m.gh = gh; m.area = gw * gh;
    m.tconf = iou_precise(pbx, pby, pbw, pbh, gx, gy, gw, gh);
    m.tb0 = gx - (float)gi;
    m.tb1 = gy - (float)gj;
    m.tb2 = logf(gw / aw);
    m.tb3 = logf(gh / ah);
    m.best = best;
    m.cell = gj * GW + gi;
    metas[b] = m;
}

// per-cell loss: coords (dx²+dy²+dw²+dh²) + masked conf term
__device__ __forceinline__ float cell_loss(float p0, float p1, float p2, float p3, float p4,
                                           float fi, float fj, bool obj,
                                           const Meta& m, float aw, float ah) {
    float tx = fast_sig(p0);
    float ty = fast_sig(p1);
    float conf = fast_sig(p4);
    float bw = fast_exp(p2) * aw;
    float bh = fast_exp(p3) * ah;
    float bx = tx + fi;
    float by = ty + fj;
    float mx = fminf(bx - bw * 0.5f, m.gxlo);
    float Mx = fmaxf(bx + bw * 0.5f, m.gxhi);
    float my = fminf(by - bh * 0.5f, m.gylo);
    float My = fmaxf(by + bh * 0.5f, m.gyhi);
    float cw = bw + m.gw - (Mx - mx);
    float ch = bh + m.gh - (My - my);
    float inter = (cw > 0.0f && ch > 0.0f) ? cw * ch : 0.0f;
    float uni = bw * bh + m.area - inter;
    float iou = inter * fast_rcp(uni);
    float cm = obj ? 2.23606797749979f : ((iou > 0.6f) ? 0.0f : 1.0f);  // sqrt(5)/0/1
    float dx = tx - (obj ? m.tb0 : 0.5f);
    float dy = ty - (obj ? m.tb1 : 0.5f);
    float dw = p2 - (obj ? m.tb2 : 0.0f);
    float dh = p3 - (obj ? m.tb3 : 0.0f);
    float dc = cm * (conf - (obj ? m.tconf : 0.0f));
    return dx * dx + dy * dy + dw * dw + dh * dh + dc * dc;
}

// USE_PARTIALS=true  → one global store per block into partials[] (needs ws room)
// USE_PARTIALS=false → one atomicAdd per block onto out[0] (verified-safe fallback)
template <bool USE_PARTIALS>
__global__ __launch_bounds__(BLK) void loss_kernel(const float* __restrict__ pred,
                                                   const Meta* __restrict__ metas,
                                                   float* __restrict__ sink) {
    unsigned t = blockIdx.x * (unsigned)BLK + threadIdx.x;
    unsigned plane = t / (unsigned)S4;        // b*25 + a, b in [0,256)
    unsigned s4 = t - plane * (unsigned)S4;
    unsigned b = plane / (unsigned)NA;
    unsigned a = plane - b * (unsigned)NA;

    // group 0: (b, a); group 1: (b+256, a) — same s4, same i/j, same anchor
    const f32x4* base0 = (const f32x4*)(pred + (size_t)plane * 5u * (unsigned)HW);
    const f32x4* base1 = base0 + (size_t)HALF_PLANES * 5u * (unsigned)S4;

    // issue all 10 streaming (nontemporal) loads before any dependent compute
    f32x4 q[5];
    f32x4 r[5];
#pragma unroll
    for (int c = 0; c < 5; ++c)
        q[c] = __builtin_nontemporal_load(base0 + s4 + (unsigned)c * (unsigned)S4);
#pragma unroll
    for (int c = 0; c < 5; ++c)
        r[c] = __builtin_nontemporal_load(base1 + s4 + (unsigned)c * (unsigned)S4);

    Meta m0 = metas[b];
    Meta m1 = metas[b + 256];
    float aw, ah;
    anchor_wh((int)a, &aw, &ah);
    bool aok0 = (a == (unsigned)m0.best);
    bool aok1 = (a == (unsigned)m1.best);

    float acc = 0.0f;
#pragma unroll
    for (int k = 0; k < 4; ++k) {
        unsigned s = s4 * 4u + (unsigned)k;
        unsigned j = s / (unsigned)GW;
        unsigned i = s - j * (unsigned)GW;
        float fi = (float)i, fj = (float)j;
        bool obj0 = aok0 && (s == (unsigned)m0.cell);
        bool obj1 = aok1 && (s == (unsigned)m1.cell);
        acc += cell_loss(q[0][k], q[1][k], q[2][k], q[3][k], q[4][k], fi, fj, obj0, m0, aw, ah);
        acc += cell_loss(r[0][k], r[1][k], r[2][k], r[3][k], r[4][k], fi, fj, obj1, m1, aw, ah);
    }

    // wave64 shuffle reduce → LDS across 4 waves → one global op per block
    for (int off = 32; off > 0; off >>= 1)
        acc += __shfl_down(acc, off, 64);
    __shared__ float sm[BLK / 64];
    int lane = (int)(threadIdx.x & 63u);
    int wv = (int)(threadIdx.x >> 6u);
    if (lane == 0) sm[wv] = acc;
    __syncthreads();
    if (threadIdx.x == 0) {
        float s = sm[0] + sm[1] + sm[2] + sm[3];
        if (USE_PARTIALS)
            sink[blockIdx.x] = s;                 // contention-free store
        else
            atomicAdd(sink, 0.5f * s);            // verified fallback path
    }
}

__global__ __launch_bounds__(BLK) void reduce_kernel(const float* __restrict__ partials,
                                                     float* __restrict__ out) {
    float acc = 0.0f;
    for (int i = (int)threadIdx.x; i < NBLOCKS; i += BLK)
        acc += partials[i];
    for (int off = 32; off > 0; off >>= 1)
        acc += __shfl_down(acc, off, 64);
    __shared__ float sm[BLK / 64];
    int lane = (int)(threadIdx.x & 63u);
    int wv = (int)(threadIdx.x >> 6u);
    if (lane == 0) sm[wv] = acc;
    __syncthreads();
    if (threadIdx.x == 0)
        out[0] = 0.5f * (sm[0] + sm[1] + sm[2] + sm[3]);
}

extern "C" void kernel_launch(void* const* d_in, const int* in_sizes, int n_in,
                              void* d_out, int out_size, void* d_ws, size_t ws_size,
                              hipStream_t stream) {
    const float* pred = (const float*)d_in[0];
    const float* target = (const float*)d_in[1];
    float* out = (float*)d_out;
    Meta* metas = (Meta*)d_ws;

    const size_t meta_bytes = sizeof(Meta) * NB;                 // 28,672 B
    const size_t need = meta_bytes + (size_t)NBLOCKS * sizeof(float);  // + 36,100 B
    const bool use_partials = ws_size >= need;                   // DON'T write OOB in d_ws

    hipMemsetAsync(d_out, 0, (size_t)out_size * sizeof(float), stream);
    meta_kernel<<<(NB + BLK - 1) / BLK, BLK, 0, stream>>>(pred, target, metas);
    if (use_partials) {
        float* partials = (float*)((char*)d_ws + meta_bytes);
        loss_kernel<true><<<NBLOCKS, BLK, 0, stream>>>(pred, metas, partials);
        reduce_kernel<<<1, BLK, 0, stream>>>(partials, out);
    } else {
        loss_kernel<false><<<NBLOCKS, BLK, 0, stream>>>(pred, metas, out);
    }
}

// Round 6
// 472.530 us; speedup vs baseline: 1.0007x; 1.0007x over previous
//
#include <hip/hip_runtime.h>
#include <math.h>

#define GW 38
#define GH 38
#define NA 25
#define NB 512
#define HW (GW * GH)                // 1444
#define S4 (HW / 4)                 // 361 float4 per channel-plane
#define PLANES (NB * NA)            // 12800 (b,a) planes
#define T_TOTAL (PLANES * S4)       // 4,620,800 threads — ONE (plane,s4) each
#define BLK 256
#define NBLOCKS (T_TOTAL / BLK)     // 18,050 loss blocks

typedef float f32x4 __attribute__((ext_vector_type(4)));

struct Meta {
    float gxlo, gxhi, gylo, gyhi;  // gx -/+ gw/2, gy -/+ gh/2
    float gw, gh, area;            // gw*gh
    float tconf, tb0, tb1, tb2, tb3;
    int   best, cell;              // cell = gj*38 + gi
};
static_assert(sizeof(Meta) == 56, "Meta layout drifted; workspace offsets depend on it");

__device__ __forceinline__ float fast_rcp(float x) { return __builtin_amdgcn_rcpf(x); }
__device__ __forceinline__ float fast_exp(float x) { return __expf(x); }          // v_exp_f32
__device__ __forceinline__ float fast_sig(float x) { return fast_rcp(1.0f + fast_exp(-x)); }

__device__ __forceinline__ float iou_precise(float x1, float y1, float w1, float h1,
                                             float x2, float y2, float w2, float h2) {
    float mx = fminf(x1 - w1 * 0.5f, x2 - w2 * 0.5f);
    float Mx = fmaxf(x1 + w1 * 0.5f, x2 + w2 * 0.5f);
    float my = fminf(y1 - h1 * 0.5f, y2 - h2 * 0.5f);
    float My = fmaxf(y1 + h1 * 0.5f, y2 + h2 * 0.5f);
    float cw = w1 + w2 - (Mx - mx);
    float ch = h1 + h2 - (My - my);
    float inter = (cw > 0.0f && ch > 0.0f) ? cw * ch : 0.0f;
    float uni = w1 * h1 + w2 * h2 - inter;
    return inter / uni;
}

// anchors = float32(_BASE) * float32(scale), scale in {0.5,0.75,1.0,1.25,1.5}
__device__ __forceinline__ void anchor_wh(int a, float* aw, float* ah) {
    const float bw[5] = {1.3221f, 3.19275f, 5.05587f, 9.47112f, 11.2364f};
    const float bh[5] = {1.73145f, 4.00944f, 8.09892f, 4.84053f, 10.0071f};
    float s = 0.5f + 0.25f * (float)(a / 5);
    *aw = bw[a % 5] * s;
    *ah = bh[a % 5] * s;
}

__global__ void meta_kernel(const float* __restrict__ pred,
                            const float* __restrict__ target,
                            Meta* __restrict__ metas) {
    int b = blockIdx.x * blockDim.x + threadIdx.x;
    if (b >= NB) return;
    float gx = target[b * 4 + 0] * (float)GW;
    float gy = target[b * 4 + 1] * (float)GH;
    float gw = target[b * 4 + 2] * (float)GW;
    float gh = target[b * 4 + 3] * (float)GH;
    int best = 0;
    float best_iou = -1.0f;
    for (int a = 0; a < NA; ++a) {
        float aw, ah;
        anchor_wh(a, &aw, &ah);
        float v = iou_precise(0.0f, 0.0f, aw, ah, 0.0f, 0.0f, gw, gh);
        if (v > best_iou) { best_iou = v; best = a; }
    }
    int gi = (int)gx;
    int gj = (int)gy;
    float aw, ah;
    anchor_wh(best, &aw, &ah);
    size_t base = (size_t)b * NA * 5 * HW + (size_t)(best * 5) * HW + gj * GW + gi;
    float p0 = pred[base + 0 * HW];
    float p1 = pred[base + 1 * HW];
    float p2 = pred[base + 2 * HW];
    float p3 = pred[base + 3 * HW];
    float pbx = 1.0f / (1.0f + expf(-p0)) + (float)gi;   // precise path (512 cells only)
    float pby = 1.0f / (1.0f + expf(-p1)) + (float)gj;
    float pbw = expf(p2) * aw;
    float pbh = expf(p3) * ah;
    Meta m;
    m.gxlo = gx - gw * 0.5f; m.gxhi = gx + gw * 0.5f;
    m.gylo = gy - gh * 0.5f; m.gyhi = gy + gh * 0.5f;
    m.gw = gw; m.gh = gh; m.area = gw * gh;
    m.tconf = iou_precise(pbx, pby, pbw, pbh, gx, gy, gw, gh);
    m.tb0 = gx - (float)gi;
    m.tb1 = gy - (float)gj;
    m.tb2 = logf(gw / aw);
    m.tb3 = logf(gh / ah);
    m.best = best;
    m.cell = gj * GW + gi;
    metas[b] = m;
}

// per-cell loss: coords (dx²+dy²+dw²+dh²) + masked conf term
__device__ __forceinline__ float cell_loss(float p0, float p1, float p2, float p3, float p4,
                                           float fi, float fj, bool obj,
                                           const Meta& m, float aw, float ah) {
    float tx = fast_sig(p0);
    float ty = fast_sig(p1);
    float conf = fast_sig(p4);
    float bw = fast_exp(p2) * aw;
    float bh = fast_exp(p3) * ah;
    float bx = tx + fi;
    float by = ty + fj;
    float mx = fminf(bx - bw * 0.5f, m.gxlo);
    float Mx = fmaxf(bx + bw * 0.5f, m.gxhi);
    float my = fminf(by - bh * 0.5f, m.gylo);
    float My = fmaxf(by + bh * 0.5f, m.gyhi);
    float cw = bw + m.gw - (Mx - mx);
    float ch = bh + m.gh - (My - my);
    float inter = (cw > 0.0f && ch > 0.0f) ? cw * ch : 0.0f;
    float uni = bw * bh + m.area - inter;
    float iou = inter * fast_rcp(uni);
    float cm = obj ? 2.23606797749979f : ((iou > 0.6f) ? 0.0f : 1.0f);  // sqrt(5)/0/1
    float dx = tx - (obj ? m.tb0 : 0.5f);
    float dy = ty - (obj ? m.tb1 : 0.5f);
    float dw = p2 - (obj ? m.tb2 : 0.0f);
    float dh = p3 - (obj ? m.tb3 : 0.0f);
    float dc = cm * (conf - (obj ? m.tconf : 0.0f));
    return dx * dx + dy * dy + dw * dw + dh * dh + dc * dc;
}

// ONE (plane, s4) per thread: 5 float4 live (20 VGPR) + 1 Meta — low register
// pressure, no spill, 8 waves/SIMD. (Previous 2-plane version held 10 float4
// + 2 Metas live across a ~3600-inst unrolled body — suspected scratch spill.)
// USE_PARTIALS=true  → one global store per block into partials[]
// USE_PARTIALS=false → one atomicAdd per block onto out[0] (fallback)
template <bool USE_PARTIALS>
__global__ __launch_bounds__(BLK) void loss_kernel(const float* __restrict__ pred,
                                                   const Meta* __restrict__ metas,
                                                   float* __restrict__ sink) {
    unsigned t = blockIdx.x * (unsigned)BLK + threadIdx.x;
    unsigned plane = t / (unsigned)S4;        // b*25 + a, b in [0,512)
    unsigned s4 = t - plane * (unsigned)S4;
    unsigned b = plane / (unsigned)NA;
    unsigned a = plane - b * (unsigned)NA;

    const f32x4* base = (const f32x4*)(pred + (size_t)plane * 5u * (unsigned)HW);

    // issue all 5 streaming (nontemporal) loads before any dependent compute
    f32x4 q[5];
#pragma unroll
    for (int c = 0; c < 5; ++c)
        q[c] = __builtin_nontemporal_load(base + s4 + (unsigned)c * (unsigned)S4);

    Meta m = metas[b];
    float aw, ah;
    anchor_wh((int)a, &aw, &ah);
    bool aok = (a == (unsigned)m.best);

    float acc = 0.0f;
#pragma unroll
    for (int k = 0; k < 4; ++k) {
        unsigned s = s4 * 4u + (unsigned)k;
        unsigned j = s / (unsigned)GW;
        unsigned i = s - j * (unsigned)GW;
        float fi = (float)i, fj = (float)j;
        bool obj = aok && (s == (unsigned)m.cell);
        acc += cell_loss(q[0][k], q[1][k], q[2][k], q[3][k], q[4][k], fi, fj, obj, m, aw, ah);
    }

    // wave64 shuffle reduce → LDS across 4 waves → one global op per block
    for (int off = 32; off > 0; off >>= 1)
        acc += __shfl_down(acc, off, 64);
    __shared__ float sm[BLK / 64];
    int lane = (int)(threadIdx.x & 63u);
    int wv = (int)(threadIdx.x >> 6u);
    if (lane == 0) sm[wv] = acc;
    __syncthreads();
    if (threadIdx.x == 0) {
        float s = sm[0] + sm[1] + sm[2] + sm[3];
        if (USE_PARTIALS)
            sink[blockIdx.x] = s;                 // contention-free store
        else
            atomicAdd(sink, 0.5f * s);            // fallback path
    }
}

__global__ __launch_bounds__(BLK) void reduce_kernel(const float* __restrict__ partials,
                                                     float* __restrict__ out) {
    float acc = 0.0f;
    for (int i = (int)threadIdx.x; i < NBLOCKS; i += BLK)
        acc += partials[i];
    for (int off = 32; off > 0; off >>= 1)
        acc += __shfl_down(acc, off, 64);
    __shared__ float sm[BLK / 64];
    int lane = (int)(threadIdx.x & 63u);
    int wv = (int)(threadIdx.x >> 6u);
    if (lane == 0) sm[wv] = acc;
    __syncthreads();
    if (threadIdx.x == 0)
        out[0] = 0.5f * (sm[0] + sm[1] + sm[2] + sm[3]);
}

extern "C" void kernel_launch(void* const* d_in, const int* in_sizes, int n_in,
                              void* d_out, int out_size, void* d_ws, size_t ws_size,
                              hipStream_t stream) {
    const float* pred = (const float*)d_in[0];
    const float* target = (const float*)d_in[1];
    float* out = (float*)d_out;
    Meta* metas = (Meta*)d_ws;

    const size_t meta_bytes = sizeof(Meta) * NB;                       // 28,672 B
    const size_t need = meta_bytes + (size_t)NBLOCKS * sizeof(float);  // + 72,200 B
    const bool use_partials = ws_size >= need;                         // never write OOB in d_ws

    hipMemsetAsync(d_out, 0, (size_t)out_size * sizeof(float), stream);
    meta_kernel<<<(NB + BLK - 1) / BLK, BLK, 0, stream>>>(pred, target, metas);
    if (use_partials) {
        float* partials = (float*)((char*)d_ws + meta_bytes);
        loss_kernel<true><<<NBLOCKS, BLK, 0, stream>>>(pred, metas, partials);
        reduce_kernel<<<1, BLK, 0, stream>>>(partials, out);
    } else {
        loss_kernel<false><<<NBLOCKS, BLK, 0, stream>>>(pred, metas, out);
    }
}